// Round 16
// baseline (739.712 us; speedup 1.0000x reference)
//
#include <hip/hip_runtime.h>
#include <math.h>

#define NB 8
#define NV 201
#define ND 256
#define NPIX (NB*NV*NV)        // 323208 (full pixel count; BN normalizer)
#define TRI  (NV*(NV+1)/2)     // 20301 upper-triangle pixels per batch (i<=j)
#define NSYM (NB*TRI)          // 162408 stored rows in symmetric mode
#define KSEL 100
#define BN_EPS 1e-5f
#define SLOPE 0.01f
#define NWTOT 180224           // total W elements: 65536+65536+32768+16384

__device__ __forceinline__ float lrelu(float v) { return v >= 0.f ? v : SLOPE * v; }

typedef _Float16 half4_t __attribute__((ext_vector_type(4)));
typedef _Float16 half8   __attribute__((ext_vector_type(8)));
typedef float    f32x4   __attribute__((ext_vector_type(4)));

// fp16x2 split, by-value (vector elements cannot bind to C++ references — r11 lesson)
__device__ __forceinline__ half4_t to_h4(float4 v) {
    half4_t h;
    h.x = (_Float16)v.x; h.y = (_Float16)v.y;
    h.z = (_Float16)v.z; h.w = (_Float16)v.w;
    return h;
}
__device__ __forceinline__ half4_t residual_h4(float4 v, half4_t h) {
    half4_t l;
    l.x = (_Float16)(v.x - (float)h.x); l.y = (_Float16)(v.y - (float)h.y);
    l.z = (_Float16)(v.z - (float)h.z); l.w = (_Float16)(v.w - (float)h.w);
    return l;
}
__device__ __forceinline__ half8 cat8(half4_t a, half4_t b) {
    half8 r;
    r[0] = a.x; r[1] = a.y; r[2] = a.z; r[3] = a.w;
    r[4] = b.x; r[5] = b.y; r[6] = b.z; r[7] = b.w;
    return r;
}

// ---- triangle index helpers (upper triangle incl. diagonal, row-major) ----
__device__ __forceinline__ int tri_base(int i) { return i * NV - (i * (i - 1)) / 2; }
__device__ __forceinline__ void tri_decode(int s, int& b, int& i, int& j) {
    b = s / TRI;
    int t = s - b * TRI;
    float disc = (float)(403 * 403) - 8.0f * (float)t;   // (2*NV+1)^2 - 8t
    int ii = (int)((403.0f - sqrtf(disc)) * 0.5f);
    if (ii < 0) ii = 0;
    if (ii > NV - 1) ii = NV - 1;
    while (ii < NV - 1 && tri_base(ii + 1) <= t) ++ii;
    while (ii > 0 && tri_base(ii) > t) --ii;
    i = ii;
    j = t - tri_base(ii) + ii;
}

__device__ __forceinline__ float4 ld4(const float* p) { return *(const float4*)p; }

__global__ void zero_stats(double* p) { p[blockIdx.x * 256 + threadIdx.x] = 0.0; }

// Pre-split ALL layer weights into hi/lo _Float16 arrays (stored in d_out scratch;
// d_out is fully overwritten by the final kernel afterwards, and this runs every
// call => graph-safe). Kills per-k-tile B staging AND per-wave B split VALU.
__global__ void split_weights(const float* __restrict__ w0, const float* __restrict__ w1,
                              const float* __restrict__ w2, const float* __restrict__ w3,
                              _Float16* __restrict__ H, _Float16* __restrict__ L)
{
    int idx = blockIdx.x * 256 + threadIdx.x;
    if (idx >= NWTOT) return;
    float v;
    if      (idx <  65536) v = w0[idx];
    else if (idx < 131072) v = w1[idx -  65536];
    else if (idx < 163840) v = w2[idx - 131072];
    else                   v = w3[idx - 163840];
    _Float16 h = (_Float16)v;
    H[idx] = h;
    L[idx] = (_Float16)(v - (float)h);
}

// MFMA GEMM, fp16x2-split (fp32-faithful): C = Ah*Bh + Ah*Bl + Al*Bh, fp32 acc.
// r14 restructure: NO LDS tiles, NO k-loop barriers. A fragments from global
// (split in registers); B fragments from the PRE-SPLIT global W arrays (L2-hot,
// same addresses across blocks). LDS ~3.5KB (wg/rbi/rbj + stats) -> occupancy
// VGPR-bound; waves drift freely, compiler pipelines loads under MFMAs.
// In-place safety: single epilogue __syncthreads — all waves' A reads complete
// before any store (replaces the per-k-tile barriers that provided this before).
template<int CIN, int COUT, int MODE>
__global__ __launch_bounds__(256)
void gemm_bn_mfma(const float* xin,                    // MODE 0 source ([8,201,256] fp32)
                  const float* in,                     // MODE 1 source (element stride 256)
                  const _Float16* __restrict__ Wh,     // [COUT, CIN] hi halves
                  const _Float16* __restrict__ Wl,     // [COUT, CIN] lo halves
                  const float* __restrict__ scale,
                  const float* __restrict__ shift,
                  float* out,                          // stride 256 (may alias `in`)
                  double* __restrict__ stat_sum,
                  double* __restrict__ stat_sq)
{
    constexpr int BM  = 128;
    constexpr int BK  = 32;
    constexpr int NCW = COUT / 32;   // col-tiles per wave (8 or 4)
    __shared__ float wg[BM];
    __shared__ int   rbi[(MODE == 0) ? BM : 1];
    __shared__ int   rbj[(MODE == 0) ? BM : 1];
    __shared__ float csum[COUT];
    __shared__ float csq[COUT];

    const int t    = threadIdx.x;
    const int lane = t & 63;
    const int wv   = t >> 6;
    const int wm   = wv >> 1;        // row half: rows [wm*64, wm*64+64)
    const int wn   = wv & 1;         // col half: cols [wn*COUT/2, +COUT/2)
    const int l15  = lane & 15;
    const int lk   = lane >> 4;      // k-group / C-row-group
    const int m0   = blockIdx.x * BM;

    for (int m = t; m < BM; m += 256) {
        int pix = m0 + m;
        int b, i, j;
        if (pix < NSYM) {
            tri_decode(pix, b, i, j);
            wg[m] = (i == j) ? 1.f : 2.f;
            if constexpr (MODE == 0) { rbi[m] = b * NV + i; rbj[m] = b * NV + j; }
        } else {
            wg[m] = 0.f;
            if constexpr (MODE == 0) { rbi[m] = 0; rbj[m] = 0; }
        }
    }
    __syncthreads();

    f32x4 acc[4][NCW];
    #pragma unroll
    for (int rt = 0; rt < 4; ++rt)
        #pragma unroll
        for (int nc = 0; nc < NCW; ++nc) {
            acc[rt][nc][0] = 0.f; acc[rt][nc][1] = 0.f;
            acc[rt][nc][2] = 0.f; acc[rt][nc][3] = 0.f;
        }

    for (int kt = 0; kt < CIN; kt += BK) {
        // ---- A fragments straight from global, split in registers ----
        float4 sc0, sc1, sh0, sh1;
        if constexpr (MODE == 1) {
            sc0 = ld4(scale + kt + lk * 8); sc1 = ld4(scale + kt + lk * 8 + 4);
            sh0 = ld4(shift + kt + lk * 8); sh1 = ld4(shift + kt + lk * 8 + 4);
        }
        half8 ah[4], alo[4];
        #pragma unroll
        for (int rt = 0; rt < 4; ++rt) {
            int m   = wm * 64 + rt * 16 + l15;
            int pix = m0 + m;
            float4 v0 = make_float4(0.f, 0.f, 0.f, 0.f);
            float4 v1 = v0;
            if (pix < NSYM) {
                if constexpr (MODE == 0) {
                    const float* pi = xin + (size_t)rbi[m] * ND + kt + lk * 8;
                    const float* pj = xin + (size_t)rbj[m] * ND + kt + lk * 8;
                    float4 xi0 = ld4(pi), xi1 = ld4(pi + 4);
                    float4 xj0 = ld4(pj), xj1 = ld4(pj + 4);
                    v0 = make_float4(fabsf(xi0.x - xj0.x), fabsf(xi0.y - xj0.y),
                                     fabsf(xi0.z - xj0.z), fabsf(xi0.w - xj0.w));
                    v1 = make_float4(fabsf(xi1.x - xj1.x), fabsf(xi1.y - xj1.y),
                                     fabsf(xi1.z - xj1.z), fabsf(xi1.w - xj1.w));
                } else {
                    const float* p = in + (size_t)pix * 256 + kt + lk * 8;
                    float4 u0 = ld4(p), u1 = ld4(p + 4);
                    v0.x = lrelu(fmaf(u0.x, sc0.x, sh0.x));
                    v0.y = lrelu(fmaf(u0.y, sc0.y, sh0.y));
                    v0.z = lrelu(fmaf(u0.z, sc0.z, sh0.z));
                    v0.w = lrelu(fmaf(u0.w, sc0.w, sh0.w));
                    v1.x = lrelu(fmaf(u1.x, sc1.x, sh1.x));
                    v1.y = lrelu(fmaf(u1.y, sc1.y, sh1.y));
                    v1.z = lrelu(fmaf(u1.z, sc1.z, sh1.z));
                    v1.w = lrelu(fmaf(u1.w, sc1.w, sh1.w));
                }
            }
            half4_t h0 = to_h4(v0), h1 = to_h4(v1);
            half4_t l0 = residual_h4(v0, h0), l1 = residual_h4(v1, h1);
            ah[rt]  = cat8(h0, h1);
            alo[rt] = cat8(l0, l1);
        }

        // ---- MFMA; B fragments from pre-split global W (L2 broadcast) ----
        #pragma unroll
        for (int nc = 0; nc < NCW; ++nc) {
            size_t boff = (size_t)(wn * (COUT / 2) + nc * 16 + l15) * CIN + kt + lk * 8;
            half8 bh = *(const half8*)(Wh + boff);
            half8 bl = *(const half8*)(Wl + boff);
            #pragma unroll
            for (int rt = 0; rt < 4; ++rt) {
                acc[rt][nc] = __builtin_amdgcn_mfma_f32_16x16x32_f16(ah[rt],  bh, acc[rt][nc], 0, 0, 0);
                acc[rt][nc] = __builtin_amdgcn_mfma_f32_16x16x32_f16(ah[rt],  bl, acc[rt][nc], 0, 0, 0);
                acc[rt][nc] = __builtin_amdgcn_mfma_f32_16x16x32_f16(alo[rt], bh, acc[rt][nc], 0, 0, 0);
            }
        }
    }

    // ---- epilogue: barrier (in-place safety: all A reads done), then stores+stats ----
    for (int n = t; n < COUT; n += 256) { csum[n] = 0.f; csq[n] = 0.f; }
    __syncthreads();

    float tsum[NCW], tsq[NCW];
    #pragma unroll
    for (int nc = 0; nc < NCW; ++nc) { tsum[nc] = 0.f; tsq[nc] = 0.f; }

    #pragma unroll
    for (int rt = 0; rt < 4; ++rt) {
        #pragma unroll
        for (int r = 0; r < 4; ++r) {
            int row = wm * 64 + rt * 16 + lk * 4 + r;   // C/D: row=(lane>>4)*4+reg
            int pix = m0 + row;
            if (pix < NSYM) {
                float wgt = wg[row];
                #pragma unroll
                for (int nc = 0; nc < NCW; ++nc) {
                    float v = acc[rt][nc][r];
                    tsum[nc] += wgt * v;
                    tsq[nc]  += wgt * v * v;
                    out[(size_t)pix * 256 + wn * (COUT / 2) + nc * 16 + l15] = v;
                }
            }
        }
    }
    #pragma unroll
    for (int nc = 0; nc < NCW; ++nc) {
        int col = wn * (COUT / 2) + nc * 16 + l15;
        atomicAdd(&csum[col], tsum[nc]);
        atomicAdd(&csq[col],  tsq[nc]);
    }
    __syncthreads();
    for (int n = t; n < COUT; n += 256) {
        atomicAdd(&stat_sum[n], (double)csum[n]);
        atomicAdd(&stat_sq[n],  (double)csq[n]);
    }
}

// double stats -> BN scale/shift (conv bias cancels exactly inside BatchNorm -> skipped)
__global__ void bn_finalize(const double* __restrict__ ssum, const double* __restrict__ ssq,
                            const float* __restrict__ g, const float* __restrict__ be,
                            float* __restrict__ scale, float* __restrict__ shift, int C)
{
    int c = threadIdx.x + blockIdx.x * blockDim.x;
    if (c < C) {
        double m = ssum[c] * (1.0 / NPIX);
        double v = ssq[c] * (1.0 / NPIX) - m * m;   // jnp.var, ddof=0
        float s = g[c] / sqrtf((float)v + BN_EPS);
        scale[c] = s;
        shift[c] = be[c] - (float)m * s;
    }
}

// BN3 + LeakyReLU + dot(w4) + b4 for every triangle row -> logit_tri[NSYM]
__global__ __launch_bounds__(256)
void logits_tri(const float* __restrict__ act,   // [NSYM, 256] (first 128 ch valid)
                const float* __restrict__ scale, const float* __restrict__ shift,
                const float* __restrict__ w4, const float* __restrict__ b4,
                float* __restrict__ lt)
{
    int s = blockIdx.x * 256 + threadIdx.x;
    if (s >= NSYM) return;
    const float* p = act + (size_t)s * 256;
    float acc = 0.f;
    #pragma unroll
    for (int c = 0; c < 128; c += 4) {
        float4 u  = ld4(p + c);
        float4 sc = *(const float4*)(scale + c);
        float4 sh = *(const float4*)(shift + c);
        float4 w  = *(const float4*)(w4 + c);
        acc += lrelu(fmaf(u.x, sc.x, sh.x)) * w.x;
        acc += lrelu(fmaf(u.y, sc.y, sh.y)) * w.y;
        acc += lrelu(fmaf(u.z, sc.z, sh.z)) * w.z;
        acc += lrelu(fmaf(u.w, sc.w, sh.w)) * w.w;
    }
    lt[s] = acc + b4[0];
}

// gather symmetric logits -> softmax over j -> top-K rank mask (stable tie-break)
__global__ __launch_bounds__(256)
void final_softmax_topk_sym(const float* __restrict__ lt, float* __restrict__ outp)
{
    __shared__ float sv[NV];
    __shared__ float red[256];
    const int row = blockIdx.x;                 // b*NV + i
    const int b   = row / NV;
    const int i   = row - b * NV;
    const int t   = threadIdx.x;

    float logit = -INFINITY;
    if (t < NV) {
        int jm = (i < t) ? i : t;
        int jM = (i < t) ? t : i;
        logit = lt[b * TRI + tri_base(jm) + (jM - jm)];
    }
    red[t] = logit;
    __syncthreads();
    #pragma unroll
    for (int off = 128; off > 0; off >>= 1) {
        if (t < off) red[t] = fmaxf(red[t], red[t + off]);
        __syncthreads();
    }
    float mx = red[0];
    __syncthreads();
    float e = (t < NV) ? expf(logit - mx) : 0.f;
    red[t] = e;
    __syncthreads();
    #pragma unroll
    for (int off = 128; off > 0; off >>= 1) {
        if (t < off) red[t] += red[t + off];
        __syncthreads();
    }
    float denom = red[0];
    __syncthreads();
    float val = e / denom;
    if (t < NV) sv[t] = val;
    __syncthreads();
    if (t < NV) {
        int rank = 0;
        for (int j = 0; j < NV; ++j) {
            float o = sv[j];
            rank += (o > val || (o == val && j < t)) ? 1 : 0;
        }
        outp[(size_t)row * NV + t] = (rank < KSEL) ? val : 0.f;
    }
}

extern "C" void kernel_launch(void* const* d_in, const int* in_sizes, int n_in,
                              void* d_out, int out_size, void* d_ws, size_t ws_size,
                              hipStream_t stream)
{
    (void)in_sizes; (void)n_in; (void)out_size; (void)ws_size;

    const float* x   = (const float*)d_in[0];
    const float* w0  = (const float*)d_in[1];
    const float* g0  = (const float*)d_in[3];
    const float* be0 = (const float*)d_in[4];
    const float* w1  = (const float*)d_in[5];
    const float* g1  = (const float*)d_in[7];
    const float* be1 = (const float*)d_in[8];
    const float* w2  = (const float*)d_in[9];
    const float* g2  = (const float*)d_in[11];
    const float* be2 = (const float*)d_in[12];
    const float* w3  = (const float*)d_in[13];
    const float* g3  = (const float*)d_in[15];
    const float* be3 = (const float*)d_in[16];
    const float* w4  = (const float*)d_in[17];
    const float* b4  = (const float*)d_in[18];
    // b0..b3 unused: conv bias cancels exactly in the following BatchNorm.

    char* ws = (char*)d_ws;
    // ws layout: [double stats 16KB][scale/shift 8KB][logit_tri 650KB][activation buf]
    double* D    = (double*)ws;                    // 4 stages x (sum[256]|sq[256])
    float*  F    = (float*)(ws + 16384);           // 4 stages x (scale[256]|shift[256])
    float*  lt   = (float*)(ws + 16384 + 8192);
    float*  buf  = (float*)(ws + 16384 + 8192 + 655360);
    float*  outp = (float*)d_out;

    // d_out doubles as W-split scratch (705KB < 1.29MB); final kernel overwrites all.
    _Float16* WH = (_Float16*)d_out;
    _Float16* WL = WH + NWTOT;

    zero_stats<<<8, 256, 0, stream>>>(D);
    split_weights<<<(NWTOT + 255) / 256, 256, 0, stream>>>(w0, w1, w2, w3, WH, WL);

    const int g128 = (NSYM + 127) / 128;   // 1269

    // L0: |xi-xj| -> conv0 (256->256)
    gemm_bn_mfma<256, 256, 0><<<g128, 256, 0, stream>>>(
        x, nullptr, WH + 0, WL + 0, nullptr, nullptr, buf, D + 0, D + 256);
    bn_finalize<<<1, 256, 0, stream>>>(D + 0, D + 256, g0, be0, F + 0, F + 256, 256);

    // L1: BN0+LReLU -> conv1 (256->256), in-place
    gemm_bn_mfma<256, 256, 1><<<g128, 256, 0, stream>>>(
        nullptr, buf, WH + 65536, WL + 65536, F + 0, F + 256, buf, D + 512, D + 768);
    bn_finalize<<<1, 256, 0, stream>>>(D + 512, D + 768, g1, be1, F + 512, F + 768, 256);

    // L2: BN1+LReLU -> conv2 (256->128), in-place
    gemm_bn_mfma<256, 128, 1><<<g128, 256, 0, stream>>>(
        nullptr, buf, WH + 131072, WL + 131072, F + 512, F + 768, buf, D + 1024, D + 1280);
    bn_finalize<<<1, 256, 0, stream>>>(D + 1024, D + 1280, g2, be2, F + 1024, F + 1280, 128);

    // L3: BN2+LReLU -> conv3 (128->128), in-place
    gemm_bn_mfma<128, 128, 1><<<g128, 256, 0, stream>>>(
        nullptr, buf, WH + 163840, WL + 163840, F + 1024, F + 1280, buf, D + 1536, D + 1792);
    bn_finalize<<<1, 256, 0, stream>>>(D + 1536, D + 1792, g3, be3, F + 1536, F + 1792, 128);

    logits_tri<<<(NSYM + 255) / 256, 256, 0, stream>>>(buf, F + 1536, F + 1792, w4, b4, lt);
    final_softmax_topk_sym<<<NB * NV, 256, 0, stream>>>(lt, outp);
}